// Round 3
// baseline (37790.445 us; speedup 1.0000x reference)
//
#include <hip/hip_runtime.h>
#include <hip/hip_bf16.h>
#include <hip/hip_cooperative_groups.h>

namespace cg = cooperative_groups;

// ---- fixed sizes ----
#define B_SZ   64
#define T_SEQ  512
#define HID    1024
#define G4     4096

typedef __attribute__((ext_vector_type(8))) short  short8;   // 8 x bf16
typedef __attribute__((ext_vector_type(4))) float  floatx4;

#define DEV __device__ __forceinline__

DEV unsigned short f2bf(float f) {          // RNE fp32 -> bf16
  unsigned int u = __float_as_uint(f);
  u += 0x7fffu + ((u >> 16) & 1u);
  return (unsigned short)(u >> 16);
}
DEV float bf2f(unsigned short b) { return __uint_as_float(((unsigned)b) << 16); }
DEV float sigm(float x) { return 1.0f / (1.0f + __expf(-x)); }
DEV float tanh_(float x) { float e = __expf(2.0f * x); return 1.0f - 2.0f / (e + 1.0f); }

// ---------- prep: W [K][N] fp32 -> WT_hi/[lo] [N][K] bf16 ----------
__global__ __launch_bounds__(256) void transpose_cast_kernel(
    const float* __restrict__ W, unsigned short* __restrict__ WTh,
    unsigned short* __restrict__ WTl, int K, int N) {
  __shared__ float tile[32][33];
  int tx = threadIdx.x & 31, ty = threadIdx.x >> 5;
  int n0 = blockIdx.x * 32, k0 = blockIdx.y * 32;
#pragma unroll
  for (int j = 0; j < 4; j++)
    tile[ty + j * 8][tx] = W[(long)(k0 + ty + j * 8) * N + n0 + tx];
  __syncthreads();
#pragma unroll
  for (int j = 0; j < 4; j++) {
    float v = tile[tx][ty + j * 8];
    unsigned short hi = f2bf(v);
    long o = (long)(n0 + ty + j * 8) * K + k0 + tx;
    WTh[o] = hi;
    if (WTl) WTl[o] = f2bf(v - bf2f(hi));
  }
}

// ---------- prep: copy h_0 (fp32) into each layer's comm slot 1 ----------
__global__ void init_h_kernel(const float* __restrict__ h0, float* Hc0, float* Hc1) {
  int i = blockIdx.x * 256 + threadIdx.x;   // [0, 131072) = [2][64][1024]
  int l = i >> 16, j = i & 65535;
  (l ? Hc1 : Hc0)[65536 + j] = h0[i];       // slot 1
}

// ---------- cooperative LSTM layer ----------
// grid 256 = mg(4 batch groups of 16) x nb(64 col groups of 16 h-cols).
// U slice in LDS (padded stride, 2-way-conflict-free). W slice in VGPRs
// (hi+lo planes for layer 0). h comm: plain fp32 global, double-buffered
// slots, one grid.sync() per step provides all ordering/visibility.
// NOTE: Xsrc and Xout ALIAS for layer 1 -> no __restrict__ on them.
template <int XKI, int HILO>     // XK = XKI*128 (L0: 4 -> 512, L1: 8 -> 1024)
__global__ __launch_bounds__(256, 1) void lstm_rec(
    const float* Xsrc,                        // rows (b*512+t)*XK fp32
    const unsigned short* __restrict__ WTh,   // [4096][XK] bf16 (hi)
    const unsigned short* __restrict__ WTl,   // [4096][XK] bf16 (lo, HILO only)
    const unsigned short* __restrict__ UT,    // [4096][1024] bf16
    float* Hc,                                // [2 slot][64][1024] fp32 comm
    const float* __restrict__ bias,           // [4096]
    const float* __restrict__ c0,             // [64][1024]
    float* Xout,                              // [64][512][1024] fp32 (delayed write)
    float* hfin, float* cfin) {               // layer-1 only (else null)
  constexpr int XK = XKI * 128;
  __shared__ __align__(16) unsigned short sU[64 * 129 * 8];  // [p][129 chunks][8], chunk 128 = pad
  __shared__ float sPart[4 * 16 * 68];                       // [wave][16 rows][68]
  cg::grid_group grid = cg::this_grid();

  const int tid = threadIdx.x;
  const int lane = tid & 63, wave = tid >> 6;
  const int quad = lane >> 4, l15 = lane & 15;
  const int nb = (int)blockIdx.x & 63, mg = (int)blockIdx.x >> 6;
  const int b0 = mg * 16;

  // stage U slice -> LDS: chunk (p, c) = UT[gcol(p)][c*8 .. c*8+7]
  for (int idx = tid; idx < 64 * 128; idx += 256) {
    int p = idx >> 7, c = idx & 127;
    int gcol = (p >> 4) * HID + nb * 16 + (p & 15);
    *(floatx4*)(sU + (p * 129 + c) * 8) =
        *(const floatx4*)(UT + (size_t)gcol * HID + (size_t)c * 8);
  }

  // W slice -> registers (B-frag layout: lane's col = its own l15)
  short8 wh[4][XKI];
  short8 wl[HILO ? 4 : 1][HILO ? XKI : 1];
#pragma unroll
  for (int nt = 0; nt < 4; nt++)
#pragma unroll
    for (int kki = 0; kki < XKI; kki++) {
      size_t o = (size_t)(nt * HID + nb * 16 + l15) * XK + wave * (XK / 4) + kki * 32 + quad * 8;
      wh[nt][kki] = *(const short8*)(WTh + o);
      if (HILO) wl[nt][kki] = *(const short8*)(WTl + o);
    }

  const int bl = tid >> 4, ii = tid & 15;
  const int bglob = b0 + bl, hcol = nb * 16 + ii;
  float c_reg = c0[bglob * HID + hcol];
  float b4[4];
#pragma unroll
  for (int g = 0; g < 4; g++) b4[g] = bias[g * HID + hcol];
  const long xout_base = ((long)bglob * T_SEQ) * HID + hcol;
  const int arow = b0 + l15;                      // A-frag row (batch) for this lane
  const float* xrow_base = Xsrc + (size_t)arow * T_SEQ * XK;
  float xo_val = 0.f;
  __syncthreads();

  for (int t = 0; t < T_SEQ; t++) {
    // delayed x-history write: all step t-1 readers passed the last grid.sync
    if (t > 0) Xout[xout_base + (long)(t - 1) * HID] = xo_val;

    floatx4 acc[4];
#pragma unroll
    for (int nt = 0; nt < 4; nt++) acc[nt] = floatx4{0.f, 0.f, 0.f, 0.f};

    // ---- x @ W ----
    const float* xrow = xrow_base + (size_t)t * XK;
#pragma unroll
    for (int kki = 0; kki < XKI; kki++) {
      int kb = wave * (XK / 4) + kki * 32 + quad * 8;
      floatx4 xa = *(const floatx4*)(xrow + kb);
      floatx4 xb = *(const floatx4*)(xrow + kb + 4);
      float xs[8] = {xa[0], xa[1], xa[2], xa[3], xb[0], xb[1], xb[2], xb[3]};
      short8 ah, al;
#pragma unroll
      for (int j = 0; j < 8; j++) {
        unsigned short hi = f2bf(xs[j]);
        ah[j] = (short)hi;
        if (HILO) al[j] = (short)f2bf(xs[j] - bf2f(hi));
      }
#pragma unroll
      for (int nt = 0; nt < 4; nt++) {
        acc[nt] = __builtin_amdgcn_mfma_f32_16x16x32_bf16(ah, wh[nt][kki], acc[nt], 0, 0, 0);
        if (HILO) {
          acc[nt] = __builtin_amdgcn_mfma_f32_16x16x32_bf16(ah, wl[nt][kki], acc[nt], 0, 0, 0);
          acc[nt] = __builtin_amdgcn_mfma_f32_16x16x32_bf16(al, wh[nt][kki], acc[nt], 0, 0, 0);
        }
      }
    }

    // ---- h @ U (fp32 h from comm slot, hi/lo split in-register) ----
    const float* hrow = Hc + (size_t)((t - 1) & 1) * 65536 + (size_t)arow * HID;
#pragma unroll
    for (int kki = 0; kki < 8; kki++) {
      int kb = wave * 256 + kki * 32 + quad * 8;
      floatx4 ha = *(const floatx4*)(hrow + kb);
      floatx4 hb = *(const floatx4*)(hrow + kb + 4);
      float hs[8] = {ha[0], ha[1], ha[2], ha[3], hb[0], hb[1], hb[2], hb[3]};
      short8 hh, hl;
#pragma unroll
      for (int j = 0; j < 8; j++) {
        unsigned short hi = f2bf(hs[j]);
        hh[j] = (short)hi;
        hl[j] = (short)f2bf(hs[j] - bf2f(hi));
      }
      int q = kb >> 3;
#pragma unroll
      for (int nt = 0; nt < 4; nt++) {
        int p = nt * 16 + l15;
        short8 bfr = *(const short8*)(sU + (p * 129 + q) * 8);
        acc[nt] = __builtin_amdgcn_mfma_f32_16x16x32_bf16(hh, bfr, acc[nt], 0, 0, 0);
        acc[nt] = __builtin_amdgcn_mfma_f32_16x16x32_bf16(hl, bfr, acc[nt], 0, 0, 0);
      }
    }

    // ---- cross-wave k-reduce via LDS ----
#pragma unroll
    for (int nt = 0; nt < 4; nt++)
#pragma unroll
      for (int r = 0; r < 4; r++)
        sPart[(wave * 16 + quad * 4 + r) * 68 + nt * 16 + l15] = acc[nt][r];
    __syncthreads();

    float g4[4];
#pragma unroll
    for (int g = 0; g < 4; g++) {
      int col = g * 16 + ii;
      g4[g] = sPart[(0 * 16 + bl) * 68 + col] + sPart[(1 * 16 + bl) * 68 + col] +
              sPart[(2 * 16 + bl) * 68 + col] + sPart[(3 * 16 + bl) * 68 + col] + b4[g];
    }

    // ---- pointwise ----
    float ig = sigm(g4[0]), fg = sigm(g4[1]), gg = tanh_(g4[2]), og = sigm(g4[3]);
    c_reg = fg * c_reg + ig * gg;
    float h = og * tanh_(c_reg);
    xo_val = h;

    // ---- publish h (plain fp32; grid.sync orders it) ----
    Hc[(size_t)(t & 1) * 65536 + bglob * HID + hcol] = h;

    grid.sync();
  }

  Xout[xout_base + (long)(T_SEQ - 1) * HID] = xo_val;
  if (hfin) {
    hfin[bglob * HID + hcol] = xo_val;
    cfin[bglob * HID + hcol] = c_reg;
  }
}

// ---------------- launch ----------------
extern "C" void kernel_launch(void* const* d_in, const int* in_sizes, int n_in,
                              void* d_out, int out_size, void* d_ws, size_t ws_size,
                              hipStream_t stream) {
  const float* X  = (const float*)d_in[0];
  const float* h0 = (const float*)d_in[1];
  const float* c0 = (const float*)d_in[2];
  const float* W0 = (const float*)d_in[3];
  const float* U0 = (const float*)d_in[4];
  const float* b0 = (const float*)d_in[5];
  const float* W1 = (const float*)d_in[6];
  const float* U1 = (const float*)d_in[7];
  const float* b1 = (const float*)d_in[8];
  float* out = (float*)d_out;

  // workspace: ~33 MB
  char* ws = (char*)d_ws;
  unsigned short* W0Th = (unsigned short*)(ws);                // 4 MB  [4096][512]
  unsigned short* W0Tl = (unsigned short*)(ws + (4L << 20));   // 4 MB
  unsigned short* U0T  = (unsigned short*)(ws + (8L << 20));   // 8 MB  [4096][1024]
  unsigned short* W1T  = (unsigned short*)(ws + (16L << 20));  // 8 MB
  unsigned short* U1T  = (unsigned short*)(ws + (24L << 20));  // 8 MB
  float* Hc0 = (float*)(ws + (32L << 20));                     // 512 KB [2][64][1024]
  float* Hc1 = (float*)(ws + (32L << 20) + (512L << 10));      // 512 KB

  transpose_cast_kernel<<<dim3(128, 16), 256, 0, stream>>>(W0, W0Th, W0Tl, 512, G4);
  transpose_cast_kernel<<<dim3(128, 32), 256, 0, stream>>>(U0, U0T, nullptr, HID, G4);
  transpose_cast_kernel<<<dim3(128, 32), 256, 0, stream>>>(W1, W1T, nullptr, HID, G4);
  transpose_cast_kernel<<<dim3(128, 32), 256, 0, stream>>>(U1, U1T, nullptr, HID, G4);
  init_h_kernel<<<512, 256, 0, stream>>>(h0, Hc0, Hc1);

  {  // layer 0: x = input X; h-history -> d_out x-region (fp32)
    const float* Xs = X;
    const unsigned short* wth = W0Th; const unsigned short* wtl = W0Tl;
    const unsigned short* ut = U0T;
    float* hc = Hc0; const float* bi = b0; const float* cc = c0;
    float* xo = out; float* hf = nullptr; float* cf = nullptr;
    void* a[] = {&Xs, &wth, &wtl, &ut, &hc, &bi, &cc, &xo, &hf, &cf};
    hipLaunchCooperativeKernel(reinterpret_cast<void*>(lstm_rec<4, 1>),
                               dim3(256), dim3(256), a, 0, stream);
  }
  {  // layer 1: x = layer-0 history in d_out (aliases Xout; delayed writes)
    const float* Xs = out;
    const unsigned short* wth = W1T; const unsigned short* wtl = W1T;
    const unsigned short* ut = U1T;
    float* hc = Hc1; const float* bi = b1; const float* cc = c0 + 65536;
    float* xo = out; float* hf = out + 33554432; float* cf = out + 33619968;
    void* a[] = {&Xs, &wth, &wtl, &ut, &hc, &bi, &cc, &xo, &hf, &cf};
    hipLaunchCooperativeKernel(reinterpret_cast<void*>(lstm_rec<8, 0>),
                               dim3(256), dim3(256), a, 0, stream);
  }
}

// Round 4
// 14669.887 us; speedup vs baseline: 2.5761x; 2.5761x over previous
//
#include <hip/hip_runtime.h>
#include <hip/hip_bf16.h>

// ---- fixed sizes ----
#define B_SZ   64
#define T_SEQ  512
#define HID    1024
#define G4     4096

typedef __attribute__((ext_vector_type(8))) short  short8;   // 8 x bf16
typedef __attribute__((ext_vector_type(4))) float  floatx4;

#define DEV __device__ __forceinline__

DEV unsigned short f2bf(float f) {          // RNE fp32 -> bf16
  unsigned int u = __float_as_uint(f);
  u += 0x7fffu + ((u >> 16) & 1u);
  return (unsigned short)(u >> 16);
}
DEV float bf2f(unsigned short b) { return __uint_as_float(((unsigned)b) << 16); }
DEV float sigm(float x) { return 1.0f / (1.0f + __expf(-x)); }
DEV float tanh_(float x) { float e = __expf(2.0f * x); return 1.0f - 2.0f / (e + 1.0f); }

// ---------- prep: W [K][N] fp32 -> WT_hi/[lo] [N][K] bf16 ----------
__global__ __launch_bounds__(256) void transpose_cast_kernel(
    const float* __restrict__ W, unsigned short* __restrict__ WTh,
    unsigned short* __restrict__ WTl, int K, int N) {
  __shared__ float tile[32][33];
  int tx = threadIdx.x & 31, ty = threadIdx.x >> 5;
  int n0 = blockIdx.x * 32, k0 = blockIdx.y * 32;
#pragma unroll
  for (int j = 0; j < 4; j++)
    tile[ty + j * 8][tx] = W[(long)(k0 + ty + j * 8) * N + n0 + tx];
  __syncthreads();
#pragma unroll
  for (int j = 0; j < 4; j++) {
    float v = tile[tx][ty + j * 8];
    unsigned short hi = f2bf(v);
    long o = (long)(n0 + ty + j * 8) * K + k0 + tx;
    WTh[o] = hi;
    if (WTl) WTl[o] = f2bf(v - bf2f(hi));
  }
}

// ---------- prep: copy h_0 (fp32) into each layer's comm slot 1 ----------
__global__ void init_h_kernel(const float* __restrict__ h0, float* Hc0, float* Hc1) {
  int i = blockIdx.x * 256 + threadIdx.x;   // [0, 131072) = [2][64][1024]
  int l = i >> 16, j = i & 65535;
  (l ? Hc1 : Hc0)[65536 + j] = h0[i];       // slot 1
}

// ---------- cooperative LSTM layer ----------
// grid 256 = mg(4 batch groups of 16) x nb(64 col groups of 16 h-cols).
// ALL cross-block deps (h comm + layer-1 Xsrc/Xout alias) are intra-mg, so we
// use a 64-block flag barrier per mg instead of grid.sync (round-3: 38us/step,
// all pipes idle -> runtime barrier was the whole cost).
// Barrier: block nb release-stores flags[nb]=t+1 (AGENT scope: compiler emits
// cross-XCD wbl2); wave0 relaxed-spins on all 64 flags (one lane each) +
// single acquire fence (buffer_inv) on exit, then __syncthreads.
// x@W is hoisted above the wait (x indep of h; writers of x row t can only
// run after our own arrival for step t, which is after our x read).
template <int XKI, int HILO>     // XK = XKI*128 (L0: 4 -> 512, L1: 8 -> 1024)
__global__ __launch_bounds__(256, 1) void lstm_rec(
    const float* Xsrc,                        // rows (b*512+t)*XK fp32
    const unsigned short* __restrict__ WTh,   // [4096][XK] bf16 (hi)
    const unsigned short* __restrict__ WTl,   // [4096][XK] bf16 (lo, HILO only)
    const unsigned short* __restrict__ UT,    // [4096][1024] bf16
    float* Hc,                                // [2 slot][64][1024] fp32 comm
    const float* __restrict__ bias,           // [4096]
    const float* __restrict__ c0,             // [64][1024]
    float* Xout,                              // [64][512][1024] fp32 (delayed write)
    float* hfin, float* cfin,                 // layer-1 only (else null)
    unsigned int* flags) {                    // [4 mg][64] step counters
  constexpr int XK = XKI * 128;
  __shared__ __align__(16) unsigned short sU[64 * 129 * 8];  // [p][129 chunks][8], chunk 128 = pad
  __shared__ float sPart[4 * 16 * 68];                       // [wave][16 rows][68]

  const int tid = threadIdx.x;
  const int lane = tid & 63, wave = tid >> 6;
  const int quad = lane >> 4, l15 = lane & 15;
  const int nb = (int)blockIdx.x & 63, mg = (int)blockIdx.x >> 6;
  const int b0 = mg * 16;
  unsigned int* fl = flags + mg * 64;

  // stage U slice -> LDS: chunk (p, c) = UT[gcol(p)][c*8 .. c*8+7]
  for (int idx = tid; idx < 64 * 128; idx += 256) {
    int p = idx >> 7, c = idx & 127;
    int gcol = (p >> 4) * HID + nb * 16 + (p & 15);
    *(floatx4*)(sU + (p * 129 + c) * 8) =
        *(const floatx4*)(UT + (size_t)gcol * HID + (size_t)c * 8);
  }

  // W slice -> registers (B-frag layout: lane's col = its own l15)
  short8 wh[4][XKI];
  short8 wl[HILO ? 4 : 1][HILO ? XKI : 1];
#pragma unroll
  for (int nt = 0; nt < 4; nt++)
#pragma unroll
    for (int kki = 0; kki < XKI; kki++) {
      size_t o = (size_t)(nt * HID + nb * 16 + l15) * XK + wave * (XK / 4) + kki * 32 + quad * 8;
      wh[nt][kki] = *(const short8*)(WTh + o);
      if (HILO) wl[nt][kki] = *(const short8*)(WTl + o);
    }

  const int bl = tid >> 4, ii = tid & 15;
  const int bglob = b0 + bl, hcol = nb * 16 + ii;
  float c_reg = c0[bglob * HID + hcol];
  float b4[4];
#pragma unroll
  for (int g = 0; g < 4; g++) b4[g] = bias[g * HID + hcol];
  const long xout_base = ((long)bglob * T_SEQ) * HID + hcol;
  const int arow = b0 + l15;                      // A-frag row (batch) for this lane
  const float* xrow_base = Xsrc + (size_t)arow * T_SEQ * XK;
  float xo_val = 0.f;
  __syncthreads();

  for (int t = 0; t < T_SEQ; t++) {
    floatx4 acc[4];
#pragma unroll
    for (int nt = 0; nt < 4; nt++) acc[nt] = floatx4{0.f, 0.f, 0.f, 0.f};

    // ---- phase 1: x @ W (independent of h; overlaps the barrier wait) ----
    const float* xrow = xrow_base + (size_t)t * XK;
#pragma unroll
    for (int kki = 0; kki < XKI; kki++) {
      int kb = wave * (XK / 4) + kki * 32 + quad * 8;
      floatx4 xa = *(const floatx4*)(xrow + kb);
      floatx4 xb = *(const floatx4*)(xrow + kb + 4);
      float xs[8] = {xa[0], xa[1], xa[2], xa[3], xb[0], xb[1], xb[2], xb[3]};
      short8 ah, al;
#pragma unroll
      for (int j = 0; j < 8; j++) {
        unsigned short hi = f2bf(xs[j]);
        ah[j] = (short)hi;
        if (HILO) al[j] = (short)f2bf(xs[j] - bf2f(hi));
      }
#pragma unroll
      for (int nt = 0; nt < 4; nt++) {
        acc[nt] = __builtin_amdgcn_mfma_f32_16x16x32_bf16(ah, wh[nt][kki], acc[nt], 0, 0, 0);
        if (HILO) {
          acc[nt] = __builtin_amdgcn_mfma_f32_16x16x32_bf16(ah, wl[nt][kki], acc[nt], 0, 0, 0);
          acc[nt] = __builtin_amdgcn_mfma_f32_16x16x32_bf16(al, wh[nt][kki], acc[nt], 0, 0, 0);
        }
      }
    }

    // ---- phase 2: wait for all mg peers to finish step t-1 ----
    if (t > 0) {
      if (tid < 64) {
        for (;;) {
          unsigned v = __hip_atomic_load(fl + tid, __ATOMIC_RELAXED,
                                         __HIP_MEMORY_SCOPE_AGENT);
          if (__ballot(v >= (unsigned)t) == ~0ull) break;
          __builtin_amdgcn_s_sleep(1);
        }
        __builtin_amdgcn_fence(__ATOMIC_ACQUIRE, "agent");
      }
      __syncthreads();
      // all step t-1 readers of Xout row t-1 have arrived -> safe (alias case)
      Xout[xout_base + (long)(t - 1) * HID] = xo_val;
    }

    // ---- phase 3: h @ U (fp32 h from comm slot, hi/lo split in-register) ----
    const float* hrow = Hc + (size_t)((t - 1) & 1) * 65536 + (size_t)arow * HID;
#pragma unroll
    for (int kki = 0; kki < 8; kki++) {
      int kb = wave * 256 + kki * 32 + quad * 8;
      floatx4 ha = *(const floatx4*)(hrow + kb);
      floatx4 hb = *(const floatx4*)(hrow + kb + 4);
      float hs[8] = {ha[0], ha[1], ha[2], ha[3], hb[0], hb[1], hb[2], hb[3]};
      short8 hh, hl;
#pragma unroll
      for (int j = 0; j < 8; j++) {
        unsigned short hi = f2bf(hs[j]);
        hh[j] = (short)hi;
        hl[j] = (short)f2bf(hs[j] - bf2f(hi));
      }
      int q = kb >> 3;
#pragma unroll
      for (int nt = 0; nt < 4; nt++) {
        int p = nt * 16 + l15;
        short8 bfr = *(const short8*)(sU + (p * 129 + q) * 8);
        acc[nt] = __builtin_amdgcn_mfma_f32_16x16x32_bf16(hh, bfr, acc[nt], 0, 0, 0);
        acc[nt] = __builtin_amdgcn_mfma_f32_16x16x32_bf16(hl, bfr, acc[nt], 0, 0, 0);
      }
    }

    // ---- phase 4: cross-wave k-reduce via LDS ----
#pragma unroll
    for (int nt = 0; nt < 4; nt++)
#pragma unroll
      for (int r = 0; r < 4; r++)
        sPart[(wave * 16 + quad * 4 + r) * 68 + nt * 16 + l15] = acc[nt][r];
    __syncthreads();

    float g4[4];
#pragma unroll
    for (int g = 0; g < 4; g++) {
      int col = g * 16 + ii;
      g4[g] = sPart[(0 * 16 + bl) * 68 + col] + sPart[(1 * 16 + bl) * 68 + col] +
              sPart[(2 * 16 + bl) * 68 + col] + sPart[(3 * 16 + bl) * 68 + col] + b4[g];
    }

    // ---- phase 5: pointwise ----
    float ig = sigm(g4[0]), fg = sigm(g4[1]), gg = tanh_(g4[2]), og = sigm(g4[3]);
    c_reg = fg * c_reg + ig * gg;
    float h = og * tanh_(c_reg);
    xo_val = h;

    // ---- phase 6: publish h ----
    Hc[(size_t)(t & 1) * 65536 + bglob * HID + hcol] = h;

    // ---- phase 7: arrive (syncthreads drains all waves' stores to L2;
    //              tid0's release store flushes that L2 cross-XCD) ----
    __syncthreads();
    if (tid == 0)
      __hip_atomic_store(fl + nb, (unsigned)(t + 1), __ATOMIC_RELEASE,
                         __HIP_MEMORY_SCOPE_AGENT);
  }

  Xout[xout_base + (long)(T_SEQ - 1) * HID] = xo_val;
  if (hfin) {
    hfin[bglob * HID + hcol] = xo_val;
    cfin[bglob * HID + hcol] = c_reg;
  }
}

// ---------------- launch ----------------
extern "C" void kernel_launch(void* const* d_in, const int* in_sizes, int n_in,
                              void* d_out, int out_size, void* d_ws, size_t ws_size,
                              hipStream_t stream) {
  const float* X  = (const float*)d_in[0];
  const float* h0 = (const float*)d_in[1];
  const float* c0 = (const float*)d_in[2];
  const float* W0 = (const float*)d_in[3];
  const float* U0 = (const float*)d_in[4];
  const float* b0 = (const float*)d_in[5];
  const float* W1 = (const float*)d_in[6];
  const float* U1 = (const float*)d_in[7];
  const float* b1 = (const float*)d_in[8];
  float* out = (float*)d_out;

  // workspace: ~33 MB + flags
  char* ws = (char*)d_ws;
  unsigned short* W0Th = (unsigned short*)(ws);                // 4 MB  [4096][512]
  unsigned short* W0Tl = (unsigned short*)(ws + (4L << 20));   // 4 MB
  unsigned short* U0T  = (unsigned short*)(ws + (8L << 20));   // 8 MB  [4096][1024]
  unsigned short* W1T  = (unsigned short*)(ws + (16L << 20));  // 8 MB
  unsigned short* U1T  = (unsigned short*)(ws + (24L << 20));  // 8 MB
  float* Hc0 = (float*)(ws + (32L << 20));                     // 512 KB [2][64][1024]
  float* Hc1 = (float*)(ws + (32L << 20) + (512L << 10));      // 512 KB
  unsigned int* fl0 = (unsigned int*)(ws + (33L << 20));       // 1 KB [4][64]
  unsigned int* fl1 = (unsigned int*)(ws + (33L << 20) + 1024);// 1 KB

  hipMemsetAsync(fl0, 0, 2048, stream);
  transpose_cast_kernel<<<dim3(128, 16), 256, 0, stream>>>(W0, W0Th, W0Tl, 512, G4);
  transpose_cast_kernel<<<dim3(128, 32), 256, 0, stream>>>(U0, U0T, nullptr, HID, G4);
  transpose_cast_kernel<<<dim3(128, 32), 256, 0, stream>>>(W1, W1T, nullptr, HID, G4);
  transpose_cast_kernel<<<dim3(128, 32), 256, 0, stream>>>(U1, U1T, nullptr, HID, G4);
  init_h_kernel<<<512, 256, 0, stream>>>(h0, Hc0, Hc1);

  {  // layer 0: x = input X; h-history -> d_out x-region (fp32)
    const float* Xs = X;
    const unsigned short* wth = W0Th; const unsigned short* wtl = W0Tl;
    const unsigned short* ut = U0T;
    float* hc = Hc0; const float* bi = b0; const float* cc = c0;
    float* xo = out; float* hf = nullptr; float* cf = nullptr;
    unsigned int* fp = fl0;
    void* a[] = {&Xs, &wth, &wtl, &ut, &hc, &bi, &cc, &xo, &hf, &cf, &fp};
    hipLaunchCooperativeKernel(reinterpret_cast<void*>(lstm_rec<4, 1>),
                               dim3(256), dim3(256), a, 0, stream);
  }
  {  // layer 1: x = layer-0 history in d_out (aliases Xout; delayed writes)
    const float* Xs = out;
    const unsigned short* wth = W1T; const unsigned short* wtl = W1T;
    const unsigned short* ut = U1T;
    float* hc = Hc1; const float* bi = b1; const float* cc = c0 + 65536;
    float* xo = out; float* hf = out + 33554432; float* cf = out + 33619968;
    unsigned int* fp = fl1;
    void* a[] = {&Xs, &wth, &wtl, &ut, &hc, &bi, &cc, &xo, &hf, &cf, &fp};
    hipLaunchCooperativeKernel(reinterpret_cast<void*>(lstm_rec<8, 0>),
                               dim3(256), dim3(256), a, 0, stream);
  }
}

// Round 5
// 11092.915 us; speedup vs baseline: 3.4067x; 1.3225x over previous
//
#include <hip/hip_runtime.h>
#include <hip/hip_bf16.h>

// ---- fixed sizes ----
#define B_SZ   64
#define T_SEQ  512
#define HID    1024
#define G4     4096

typedef __attribute__((ext_vector_type(8))) short  short8;   // 8 x bf16
typedef __attribute__((ext_vector_type(4))) float  floatx4;

#define DEV __device__ __forceinline__

DEV unsigned short f2bf(float f) {          // RNE fp32 -> bf16
  unsigned int u = __float_as_uint(f);
  u += 0x7fffu + ((u >> 16) & 1u);
  return (unsigned short)(u >> 16);
}
DEV float bf2f(unsigned short b) { return __uint_as_float(((unsigned)b) << 16); }
DEV float sigm(float x) { return 1.0f / (1.0f + __expf(-x)); }
DEV float tanh_(float x) { float e = __expf(2.0f * x); return 1.0f - 2.0f / (e + 1.0f); }

// ---------- prep: W [K][N] fp32 -> WT_hi/[lo] [N][K] bf16 ----------
__global__ __launch_bounds__(256) void transpose_cast_kernel(
    const float* __restrict__ W, unsigned short* __restrict__ WTh,
    unsigned short* __restrict__ WTl, int K, int N) {
  __shared__ float tile[32][33];
  int tx = threadIdx.x & 31, ty = threadIdx.x >> 5;
  int n0 = blockIdx.x * 32, k0 = blockIdx.y * 32;
#pragma unroll
  for (int j = 0; j < 4; j++)
    tile[ty + j * 8][tx] = W[(long)(k0 + ty + j * 8) * N + n0 + tx];
  __syncthreads();
#pragma unroll
  for (int j = 0; j < 4; j++) {
    float v = tile[tx][ty + j * 8];
    unsigned short hi = f2bf(v);
    long o = (long)(n0 + ty + j * 8) * K + k0 + tx;
    WTh[o] = hi;
    if (WTl) WTl[o] = f2bf(v - bf2f(hi));
  }
}

// ---------- prep: copy h_0 (fp32) into each layer's comm slot 1 ----------
__global__ void init_h_kernel(const float* __restrict__ h0, float* Hc0, float* Hc1) {
  int i = blockIdx.x * 256 + threadIdx.x;   // [0, 131072) = [2][64][1024]
  int l = i >> 16, j = i & 65535;
  (l ? Hc1 : Hc0)[65536 + j] = h0[i];       // slot 1
}

// ---------- cooperative LSTM layer ----------
// grid 256 = mg(4 batch groups of 16) x nb(64 col groups of 16 h-cols).
// Round-5 protocol: NO fences anywhere (round-4's per-step acquire buffer_inv
// nuked the XCD L2 -> 1 GB refetch + 14.6us/step). All cross-block traffic
// (h comm, flags) uses agent-scope RELAXED atomics = sc0/sc1 cache-bypass ops
// completing at L3. Ordering: __syncthreads drains each wave's vmcnt (h
// stores reach L3) before tid0's flag store; consumer h loads are control-
// dependent on the flag poll and can't hit stale L1/L2 (those addrs are never
// cache-accessed). Per-wave waits: wave w's k-slice needs only producers
// [16w,16w+16). Xout alias write sits after the post-sPart __syncthreads,
// where all 64 flags have been collectively observed.
template <int XKI, int HILO>     // XK = XKI*128 (L0: 4 -> 512, L1: 8 -> 1024)
__global__ __launch_bounds__(256, 1) void lstm_rec(
    const float* Xsrc,                        // rows (b*512+t)*XK fp32 (aliases Xout in L1!)
    const unsigned short* __restrict__ WTh,   // [4096][XK] bf16 (hi)
    const unsigned short* __restrict__ WTl,   // [4096][XK] bf16 (lo, HILO only)
    const unsigned short* __restrict__ UT,    // [4096][1024] bf16
    float* Hc,                                // [2 slot][64][1024] fp32 comm (bypass-only)
    const float* __restrict__ bias,           // [4096]
    const float* __restrict__ c0,             // [64][1024]
    float* Xout,                              // [64][512][1024] fp32 (delayed write)
    float* hfin, float* cfin,                 // layer-1 only (else null)
    unsigned int* flags) {                    // [4 mg][64] step counters (bypass-only)
  constexpr int XK = XKI * 128;
  __shared__ __align__(16) unsigned short sU[64 * 129 * 8];  // [p][129 chunks][8], chunk 128 = pad
  __shared__ float sPart[4 * 16 * 68];                       // [wave][16 rows][68]

  const int tid = threadIdx.x;
  const int lane = tid & 63, wave = tid >> 6;
  const int quad = lane >> 4, l15 = lane & 15;
  const int nb = (int)blockIdx.x & 63, mg = (int)blockIdx.x >> 6;
  const int b0 = mg * 16;
  unsigned int* fl = flags + mg * 64;

  // stage U slice -> LDS: chunk (p, c) = UT[gcol(p)][c*8 .. c*8+7]
  for (int idx = tid; idx < 64 * 128; idx += 256) {
    int p = idx >> 7, c = idx & 127;
    int gcol = (p >> 4) * HID + nb * 16 + (p & 15);
    *(floatx4*)(sU + (p * 129 + c) * 8) =
        *(const floatx4*)(UT + (size_t)gcol * HID + (size_t)c * 8);
  }

  // W slice -> registers (B-frag layout: lane's col = its own l15)
  short8 wh[4][XKI];
  short8 wl[HILO ? 4 : 1][HILO ? XKI : 1];
#pragma unroll
  for (int nt = 0; nt < 4; nt++)
#pragma unroll
    for (int kki = 0; kki < XKI; kki++) {
      size_t o = (size_t)(nt * HID + nb * 16 + l15) * XK + wave * (XK / 4) + kki * 32 + quad * 8;
      wh[nt][kki] = *(const short8*)(WTh + o);
      if (HILO) wl[nt][kki] = *(const short8*)(WTl + o);
    }

  const int bl = tid >> 4, ii = tid & 15;
  const int bglob = b0 + bl, hcol = nb * 16 + ii;
  float c_reg = c0[bglob * HID + hcol];
  float b4[4];
#pragma unroll
  for (int g = 0; g < 4; g++) b4[g] = bias[g * HID + hcol];
  const long xout_base = ((long)bglob * T_SEQ) * HID + hcol;
  const int arow = b0 + l15;                      // A-frag row (batch) for this lane
  const float* xrow_base = Xsrc + (size_t)arow * T_SEQ * XK;
  const int fidx = wave * 16 + l15;               // this wave's producer set
  float xo_val = 0.f;
  __syncthreads();

  for (int t = 0; t < T_SEQ; t++) {
    floatx4 acc[4];
#pragma unroll
    for (int nt = 0; nt < 4; nt++) acc[nt] = floatx4{0.f, 0.f, 0.f, 0.f};

    // ---- phase 1: x @ W (independent of h; overlaps the flag wait) ----
    const float* xrow = xrow_base + (size_t)t * XK;
#pragma unroll
    for (int kki = 0; kki < XKI; kki++) {
      int kb = wave * (XK / 4) + kki * 32 + quad * 8;
      floatx4 xa = *(const floatx4*)(xrow + kb);
      floatx4 xb = *(const floatx4*)(xrow + kb + 4);
      float xs[8] = {xa[0], xa[1], xa[2], xa[3], xb[0], xb[1], xb[2], xb[3]};
      short8 ah, al;
#pragma unroll
      for (int j = 0; j < 8; j++) {
        unsigned short hi = f2bf(xs[j]);
        ah[j] = (short)hi;
        if (HILO) al[j] = (short)f2bf(xs[j] - bf2f(hi));
      }
#pragma unroll
      for (int nt = 0; nt < 4; nt++) {
        acc[nt] = __builtin_amdgcn_mfma_f32_16x16x32_bf16(ah, wh[nt][kki], acc[nt], 0, 0, 0);
        if (HILO) {
          acc[nt] = __builtin_amdgcn_mfma_f32_16x16x32_bf16(ah, wl[nt][kki], acc[nt], 0, 0, 0);
          acc[nt] = __builtin_amdgcn_mfma_f32_16x16x32_bf16(al, wh[nt][kki], acc[nt], 0, 0, 0);
        }
      }
    }

    // ---- phase 2: per-wave wait for this wave's 16 producers (step t-1) ----
    if (t > 0) {
      for (;;) {
        unsigned v = __hip_atomic_load(fl + fidx, __ATOMIC_RELAXED,
                                       __HIP_MEMORY_SCOPE_AGENT);
        if (__ballot(v >= (unsigned)t) == ~0ull) break;
        __builtin_amdgcn_s_sleep(1);
      }
      __asm__ __volatile__("" ::: "memory");   // compiler barrier only
    }

    // ---- phase 3: h @ U (bypass dword loads; hi/lo split in-register) ----
    const float* hrow = Hc + (size_t)((t - 1) & 1) * 65536 + (size_t)arow * HID;
#pragma unroll
    for (int kki = 0; kki < 8; kki++) {
      int kb = wave * 256 + kki * 32 + quad * 8;
      const float* hp = hrow + kb;
      float hs[8];
#pragma unroll
      for (int j = 0; j < 8; j++)
        hs[j] = __hip_atomic_load(hp + j, __ATOMIC_RELAXED, __HIP_MEMORY_SCOPE_AGENT);
      short8 hh, hl;
#pragma unroll
      for (int j = 0; j < 8; j++) {
        unsigned short hi = f2bf(hs[j]);
        hh[j] = (short)hi;
        hl[j] = (short)f2bf(hs[j] - bf2f(hi));
      }
      int q = kb >> 3;
#pragma unroll
      for (int nt = 0; nt < 4; nt++) {
        int p = nt * 16 + l15;
        short8 bfr = *(const short8*)(sU + (p * 129 + q) * 8);
        acc[nt] = __builtin_amdgcn_mfma_f32_16x16x32_bf16(hh, bfr, acc[nt], 0, 0, 0);
        acc[nt] = __builtin_amdgcn_mfma_f32_16x16x32_bf16(hl, bfr, acc[nt], 0, 0, 0);
      }
    }

    // ---- phase 4: cross-wave k-reduce via LDS ----
#pragma unroll
    for (int nt = 0; nt < 4; nt++)
#pragma unroll
      for (int r = 0; r < 4; r++)
        sPart[(wave * 16 + quad * 4 + r) * 68 + nt * 16 + l15] = acc[nt][r];
    __syncthreads();
    // all 4 waves passed their spins -> all 64 flags >= t observed -> the
    // delayed Xout write (row t-1) is race-free even in the aliased L1 case.
    if (t > 0) Xout[xout_base + (long)(t - 1) * HID] = xo_val;

    float g4[4];
#pragma unroll
    for (int g = 0; g < 4; g++) {
      int col = g * 16 + ii;
      g4[g] = sPart[(0 * 16 + bl) * 68 + col] + sPart[(1 * 16 + bl) * 68 + col] +
              sPart[(2 * 16 + bl) * 68 + col] + sPart[(3 * 16 + bl) * 68 + col] + b4[g];
    }

    // ---- phase 5: pointwise ----
    float ig = sigm(g4[0]), fg = sigm(g4[1]), gg = tanh_(g4[2]), og = sigm(g4[3]);
    c_reg = fg * c_reg + ig * gg;
    float h = og * tanh_(c_reg);
    xo_val = h;

    // ---- phase 6: publish h (bypass store, completes at L3) ----
    __hip_atomic_store(Hc + (size_t)(t & 1) * 65536 + bglob * HID + hcol, h,
                       __ATOMIC_RELAXED, __HIP_MEMORY_SCOPE_AGENT);

    // ---- phase 7: arrive. __syncthreads drains every wave's vmcnt (h
    //      stores acked at L3), then the flag store publishes step t. ----
    __syncthreads();
    if (tid == 0)
      __hip_atomic_store(fl + nb, (unsigned)(t + 1), __ATOMIC_RELAXED,
                         __HIP_MEMORY_SCOPE_AGENT);
  }

  Xout[xout_base + (long)(T_SEQ - 1) * HID] = xo_val;
  if (hfin) {
    hfin[bglob * HID + hcol] = xo_val;
    cfin[bglob * HID + hcol] = c_reg;
  }
}

// ---------------- launch ----------------
extern "C" void kernel_launch(void* const* d_in, const int* in_sizes, int n_in,
                              void* d_out, int out_size, void* d_ws, size_t ws_size,
                              hipStream_t stream) {
  const float* X  = (const float*)d_in[0];
  const float* h0 = (const float*)d_in[1];
  const float* c0 = (const float*)d_in[2];
  const float* W0 = (const float*)d_in[3];
  const float* U0 = (const float*)d_in[4];
  const float* b0 = (const float*)d_in[5];
  const float* W1 = (const float*)d_in[6];
  const float* U1 = (const float*)d_in[7];
  const float* b1 = (const float*)d_in[8];
  float* out = (float*)d_out;

  // workspace: ~33 MB + flags
  char* ws = (char*)d_ws;
  unsigned short* W0Th = (unsigned short*)(ws);                // 4 MB  [4096][512]
  unsigned short* W0Tl = (unsigned short*)(ws + (4L << 20));   // 4 MB
  unsigned short* U0T  = (unsigned short*)(ws + (8L << 20));   // 8 MB  [4096][1024]
  unsigned short* W1T  = (unsigned short*)(ws + (16L << 20));  // 8 MB
  unsigned short* U1T  = (unsigned short*)(ws + (24L << 20));  // 8 MB
  float* Hc0 = (float*)(ws + (32L << 20));                     // 512 KB [2][64][1024]
  float* Hc1 = (float*)(ws + (32L << 20) + (512L << 10));      // 512 KB
  unsigned int* fl0 = (unsigned int*)(ws + (33L << 20));       // 1 KB [4][64]
  unsigned int* fl1 = (unsigned int*)(ws + (33L << 20) + 1024);// 1 KB

  hipMemsetAsync(fl0, 0, 2048, stream);
  transpose_cast_kernel<<<dim3(128, 16), 256, 0, stream>>>(W0, W0Th, W0Tl, 512, G4);
  transpose_cast_kernel<<<dim3(128, 32), 256, 0, stream>>>(U0, U0T, nullptr, HID, G4);
  transpose_cast_kernel<<<dim3(128, 32), 256, 0, stream>>>(W1, W1T, nullptr, HID, G4);
  transpose_cast_kernel<<<dim3(128, 32), 256, 0, stream>>>(U1, U1T, nullptr, HID, G4);
  init_h_kernel<<<512, 256, 0, stream>>>(h0, Hc0, Hc1);

  {  // layer 0: x = input X; h-history -> d_out x-region (fp32)
    const float* Xs = X;
    const unsigned short* wth = W0Th; const unsigned short* wtl = W0Tl;
    const unsigned short* ut = U0T;
    float* hc = Hc0; const float* bi = b0; const float* cc = c0;
    float* xo = out; float* hf = nullptr; float* cf = nullptr;
    unsigned int* fp = fl0;
    void* a[] = {&Xs, &wth, &wtl, &ut, &hc, &bi, &cc, &xo, &hf, &cf, &fp};
    hipLaunchCooperativeKernel(reinterpret_cast<void*>(lstm_rec<4, 1>),
                               dim3(256), dim3(256), a, 0, stream);
  }
  {  // layer 1: x = layer-0 history in d_out (aliases Xout; delayed writes)
    const float* Xs = out;
    const unsigned short* wth = W1T; const unsigned short* wtl = W1T;
    const unsigned short* ut = U1T;
    float* hc = Hc1; const float* bi = b1; const float* cc = c0 + 65536;
    float* xo = out; float* hf = out + 33554432; float* cf = out + 33619968;
    unsigned int* fp = fl1;
    void* a[] = {&Xs, &wth, &wtl, &ut, &hc, &bi, &cc, &xo, &hf, &cf, &fp};
    hipLaunchCooperativeKernel(reinterpret_cast<void*>(lstm_rec<8, 0>),
                               dim3(256), dim3(256), a, 0, stream);
  }
}